// Round 9
// baseline (3745.288 us; speedup 1.0000x reference)
//
#include <hip/hip_runtime.h>
#include <hip/hip_bf16.h>

// ViT-S/16 forward, B=128. Inputs/outputs fp32 (per reference). Internal:
// weights+activations bf16 for MFMA, residual stream fp32, LN/softmax fp32.
// R11: XCD-aware bijective block swizzle (T1/m204). R12: gelu tanh + head-
// major QKV. R13: 8-wave 512-thread GEMM blocks (3228 us). Per-GEMM
// efficiency is floored (~440 TF; Mfma 17%, HBM 18%, VALU 53%, Occ 69%).
// R14: kill pipeline overhead instead -- k_gemm_ln: BM=32 x BN=384 full-row
// blocks for out-proj and fc2. Epilogue does h += v, then block-wide row
// LayerNorm (quad-shfl + LDS partials) and writes xn directly. Deletes all
// 24 in-loop k_ln dispatches and their 38.7 MB h re-read each.

#define S_ 197
#define D_ 384
#define BATCH 128

using bf16 = __hip_bfloat16;
typedef __attribute__((ext_vector_type(8))) __bf16 bf16x8;
typedef __attribute__((ext_vector_type(4))) float f32x4;

#if __has_builtin(__builtin_amdgcn_global_load_lds)
#define HAVE_GLL 1
__device__ __forceinline__ void gll16(const bf16* g, __bf16* l) {
  __builtin_amdgcn_global_load_lds(
      (const __attribute__((address_space(1))) void*)g,
      (__attribute__((address_space(3))) void*)l, 16, 0, 0);
}
#else
#define HAVE_GLL 0
#endif

// fp32 -> bf16 (RN), 4 elements/thread. n must be a multiple of 4.
__global__ __launch_bounds__(256) void k_f2b(const float* __restrict__ src,
                                             bf16* __restrict__ dst, int n4) {
  int i = blockIdx.x * 256 + threadIdx.x;
  if (i >= n4) return;
  float4 v = ((const float4*)src)[i];
  bf16 o[4] = {__float2bfloat16(v.x), __float2bfloat16(v.y),
               __float2bfloat16(v.z), __float2bfloat16(v.w)};
  ((uint2*)dst)[i] = *(uint2*)o;
}

__global__ __launch_bounds__(256) void k_embed_init(const float* __restrict__ cls,
                                                    const float* __restrict__ pos,
                                                    float* __restrict__ h) {
  int idx = blockIdx.x * 256 + threadIdx.x;
  if (idx >= BATCH * S_ * D_) return;
  int d = idx % D_;
  int s = (idx / D_) % S_;
  float v = pos[s * D_ + d];
  if (s == 0) v += cls[d];
  h[idx] = v;
}

__global__ __launch_bounds__(256) void k_patchify(const float* __restrict__ x,
                                                  bf16* __restrict__ patches) {
  int idx = blockIdx.x * 256 + threadIdx.x;
  if (idx >= BATCH * 196 * 768) return;
  int f = idx % 768;
  int n = (idx / 768) % 196;
  int b = idx / (768 * 196);
  int c = f >> 8, rem = f & 255, dy = rem >> 4, dx = rem & 15;
  int py = n / 14, px = n % 14;
  patches[idx] = __float2bfloat16(
      x[(((size_t)b * 3 + c) * 224 + py * 16 + dy) * 224 + px * 16 + dx]);
}

// out[M,N] = X[M,K] @ W[N,K]^T + bias.  Grid: (N/128, M/128), 512 threads.
// 8 waves in 2x4: wave tile 64 rows x 32 cols, acc[4][2].
// MODE 0: out=bf16(v); MODE 1: out=bf16(gelu_tanh(v));
// MODE 2: res(f32)+=v (remap!=0: row r -> r + r/196 + 1)
// MODE 3: out=bf16(v) head-major QKV.
template <int MODE>
__global__ __launch_bounds__(512, 6) void k_gemm(const bf16* __restrict__ X,
                                                 const bf16* __restrict__ W,
                                                 const float* __restrict__ bias,
                                                 bf16* __restrict__ out,
                                                 float* __restrict__ res,
                                                 int N, int K, int remap) {
  __shared__ __align__(16) __bf16 As[2][128 * 32];
  __shared__ __align__(16) __bf16 Bs[2][128 * 32];
  const int tid = threadIdx.x;

  // XCD-aware bijective swizzle (T1/m204)
  const int gx = gridDim.x;
  const int nwg = gx * gridDim.y;
  const int lid = blockIdx.y * gx + blockIdx.x;
  const int xcd = lid & 7, sseq = lid >> 3;
  const int q8 = nwg >> 3, r8 = nwg & 7;
  const int start = xcd * q8 + (xcd < r8 ? xcd : r8);
  const int wgid = start + sseq;
  const int m0 = (wgid / gx) * 128, n0 = (wgid % gx) * 128;

  const int lane = tid & 63, w = tid >> 6;     // w in 0..7
  const int wr = w >> 2, wc = w & 3;           // 2x4 wave grid
  const int l16 = lane & 15, quad = lane >> 4;
  f32x4 acc[4][2] = {};

  const int srow = w * 16 + (lane >> 2);
  const int scol = (((lane & 3) ^ ((lane >> 3) & 3)) << 3);
  const bf16* Ag = X + (size_t)(m0 + srow) * K + scol;
  const bf16* Bg = W + (size_t)(n0 + srow) * K + scol;
  const int ldsW = w * 512;

  const int jx8 = ((quad ^ ((l16 >> 1) & 3)) << 3);
  const int aoff = (wr * 64 + l16) * 32 + jx8;
  const int boff = (wc * 32 + l16) * 32 + jx8;

#if HAVE_GLL
#define STAGE(buf, k0)                 \
  do {                                 \
    gll16(Ag + (k0), &As[buf][ldsW]);  \
    gll16(Bg + (k0), &Bs[buf][ldsW]);  \
  } while (0)
#else
#define STAGE(buf, k0)                                                \
  do {                                                                \
    *(uint4*)(&As[buf][ldsW + (lane >> 2) * 32 + (lane & 3) * 8]) =   \
        *(const uint4*)(Ag + (k0));                                   \
    *(uint4*)(&Bs[buf][ldsW + (lane >> 2) * 32 + (lane & 3) * 8]) =   \
        *(const uint4*)(Bg + (k0));                                   \
  } while (0)
#endif

  STAGE(0, 0);
  __syncthreads();
  for (int k0 = 0; k0 < K; k0 += 32) {
    const int cb = (k0 >> 5) & 1;
    if (k0 + 32 < K) STAGE(cb ^ 1, k0 + 32);
    bf16x8 av[4], bv[2];
#pragma unroll
    for (int i = 0; i < 4; i++)
      av[i] = *(const bf16x8*)(&As[cb][aoff + i * 512]);
#pragma unroll
    for (int j = 0; j < 2; j++)
      bv[j] = *(const bf16x8*)(&Bs[cb][boff + j * 512]);
#pragma unroll
    for (int i = 0; i < 4; i++)
#pragma unroll
      for (int j = 0; j < 2; j++)
        acc[i][j] = __builtin_amdgcn_mfma_f32_16x16x32_bf16(av[i], bv[j], acc[i][j], 0, 0, 0);
    __syncthreads();
  }
#undef STAGE

  float bvv[2];
#pragma unroll
  for (int j = 0; j < 2; j++)
    bvv[j] = bias[n0 + wc * 32 + j * 16 + l16];
#pragma unroll
  for (int i = 0; i < 4; i++) {
    const int rbase = m0 + wr * 64 + i * 16 + quad * 4;
#pragma unroll
    for (int j = 0; j < 2; j++) {
      const int col = n0 + wc * 32 + j * 16 + l16;
      const int which = col / 384;
      const int hd2 = (col >> 6) % 6;
      const int d = col & 63;
#pragma unroll
      for (int r = 0; r < 4; r++) {
        float v = acc[i][j][r] + bvv[j];
        int rw = rbase + r;
        if (MODE == 0) {
          out[(size_t)rw * N + col] = __float2bfloat16(v);
        } else if (MODE == 1) {
          float t = 0.7978845608f * v * (1.f + 0.044715f * v * v);
          float e = __expf(2.f * t);
          float th = 1.f - 2.f / (e + 1.f);
          out[(size_t)rw * N + col] = __float2bfloat16(0.5f * v * (1.f + th));
        } else if (MODE == 3) {
          int b2 = rw / 197;
          int s = rw - b2 * 197;
          out[((size_t)(which * 768 + b2 * 6 + hd2) * 197 + s) * 64 + d] =
              __float2bfloat16(v);
        } else {
          int hr = remap ? (rw + rw / 196 + 1) : rw;
          res[(size_t)hr * N + col] += v;
        }
      }
    }
  }
}

// Full-row GEMM + residual-add + fused row LayerNorm.
// out-tile 32 x 384 (BM=32, BN=384=N), grid (M/32) 1-D, 256 threads.
// 4 waves in 1x4: wave tile 32 rows x 96 cols, acc[2][6].
// h[r] += A@W^T + bias; then xn[r] = LN(h[r]) * g + b  (row fully in-block).
__global__ __launch_bounds__(256, 4) void k_gemm_ln(
    const bf16* __restrict__ X, const bf16* __restrict__ W,
    const float* __restrict__ bias, float* __restrict__ res,
    bf16* __restrict__ xn, const float* __restrict__ lng,
    const float* __restrict__ lnb, int K) {
  __shared__ __align__(16) __bf16 As[2][32 * 32];
  __shared__ __align__(16) __bf16 Bs[2][384 * 32];
  __shared__ float ps[32][4], qs[32][4];
  const int tid = threadIdx.x;
  const int m0 = blockIdx.x * 32;
  const int lane = tid & 63, w = tid >> 6;   // 4 waves
  const int wc = w;                          // 1x4 wave grid (cols)
  const int l16 = lane & 15, quad = lane >> 4;
  f32x4 acc[2][6] = {};

  // staging lane mapping (rows of 32 elems = 4 chunks of 8):
  const int scol = (((lane & 3) ^ ((lane >> 3) & 3)) << 3);
  // A: waves 0..1 stage rows w*16 + (lane>>2)  (32 rows total)
  const bf16* Ag = X + (size_t)(m0 + w * 16 + (lane >> 2)) * K + scol;
  // B: all waves, 6 ops; op o covers rows o*64 + w*16 + (lane>>2)
  const bf16* Bg = W + (size_t)(w * 16 + (lane >> 2)) * K + scol;

  const int jx8 = ((quad ^ ((l16 >> 1) & 3)) << 3);
  const int aoff = l16 * 32 + jx8;                 // + i*512
  const int boff = (wc * 96 + l16) * 32 + jx8;     // + j*512

#if HAVE_GLL
#define STAGEL(buf, k0)                                                   \
  do {                                                                    \
    if (w < 2) gll16(Ag + (k0), &As[buf][w * 512]);                       \
    _Pragma("unroll") for (int o = 0; o < 6; o++)                         \
        gll16(Bg + (size_t)o * 64 * K + (k0),                             \
              &Bs[buf][(o * 64 + w * 16) * 32]);                          \
  } while (0)
#else
#define STAGEL(buf, k0)                                                   \
  do {                                                                    \
    if (w < 2)                                                            \
      *(uint4*)(&As[buf][(w * 16 + (lane >> 2)) * 32 + (lane & 3) * 8]) = \
          *(const uint4*)(Ag + (k0));                                     \
    _Pragma("unroll") for (int o = 0; o < 6; o++)                         \
        *(uint4*)(&Bs[buf][(o * 64 + w * 16 + (lane >> 2)) * 32 +         \
                           (lane & 3) * 8]) =                             \
            *(const uint4*)(Bg + (size_t)o * 64 * K + (k0));              \
  } while (0)
#endif

  STAGEL(0, 0);
  __syncthreads();
  for (int k0 = 0; k0 < K; k0 += 32) {
    const int cb = (k0 >> 5) & 1;
    if (k0 + 32 < K) STAGEL(cb ^ 1, k0 + 32);
    bf16x8 av[2], bv[6];
#pragma unroll
    for (int i = 0; i < 2; i++)
      av[i] = *(const bf16x8*)(&As[cb][aoff + i * 512]);
#pragma unroll
    for (int j = 0; j < 6; j++)
      bv[j] = *(const bf16x8*)(&Bs[cb][boff + j * 512]);
#pragma unroll
    for (int i = 0; i < 2; i++)
#pragma unroll
      for (int j = 0; j < 6; j++)
        acc[i][j] = __builtin_amdgcn_mfma_f32_16x16x32_bf16(av[i], bv[j], acc[i][j], 0, 0, 0);
    __syncthreads();
  }
#undef STAGEL

  // epilogue: h += v (keep new h in acc), then row LN -> xn
  float bb[6];
#pragma unroll
  for (int j = 0; j < 6; j++) bb[j] = bias[wc * 96 + j * 16 + l16];
#pragma unroll
  for (int i = 0; i < 2; i++)
#pragma unroll
    for (int r = 0; r < 4; r++) {
      const int hr = m0 + i * 16 + quad * 4 + r;
#pragma unroll
      for (int j = 0; j < 6; j++) {
        const int col = wc * 96 + j * 16 + l16;
        float nv = res[(size_t)hr * 384 + col] + acc[i][j][r] + bb[j];
        res[(size_t)hr * 384 + col] = nv;
        acc[i][j][r] = nv;
      }
    }
  // per-row partial sums (this thread covers 6 cols of each of its 8 rows)
  float s_[2][4], q_[2][4];
#pragma unroll
  for (int i = 0; i < 2; i++)
#pragma unroll
    for (int r = 0; r < 4; r++) {
      float s = 0.f, q = 0.f;
#pragma unroll
      for (int j = 0; j < 6; j++) {
        float v = acc[i][j][r];
        s += v;
        q += v * v;
      }
#pragma unroll
      for (int o = 1; o < 16; o <<= 1) {
        s += __shfl_xor(s, o);
        q += __shfl_xor(q, o);
      }
      s_[i][r] = s;
      q_[i][r] = q;
    }
  if (l16 == 0) {
#pragma unroll
    for (int i = 0; i < 2; i++)
#pragma unroll
      for (int r = 0; r < 4; r++) {
        const int lr = i * 16 + quad * 4 + r;
        ps[lr][w] = s_[i][r];
        qs[lr][w] = q_[i][r];
      }
  }
  __syncthreads();
  float gg[6], bt[6];
#pragma unroll
  for (int j = 0; j < 6; j++) {
    gg[j] = lng[wc * 96 + j * 16 + l16];
    bt[j] = lnb[wc * 96 + j * 16 + l16];
  }
#pragma unroll
  for (int i = 0; i < 2; i++)
#pragma unroll
    for (int r = 0; r < 4; r++) {
      const int lr = i * 16 + quad * 4 + r;
      const float s = ps[lr][0] + ps[lr][1] + ps[lr][2] + ps[lr][3];
      const float q = qs[lr][0] + qs[lr][1] + qs[lr][2] + qs[lr][3];
      const float mean = s * (1.f / 384.f);
      const float var = q * (1.f / 384.f) - mean * mean;
      const float rstd = rsqrtf(var + 1e-5f);
      const int hr = m0 + lr;
#pragma unroll
      for (int j = 0; j < 6; j++) {
        const int col = wc * 96 + j * 16 + l16;
        xn[(size_t)hr * 384 + col] =
            __float2bfloat16((acc[i][j][r] - mean) * rstd * gg[j] + bt[j]);
      }
    }
}

__global__ __launch_bounds__(128) void k_ln(const float* __restrict__ h,
                                            const float* __restrict__ g,
                                            const float* __restrict__ bt,
                                            bf16* __restrict__ xn) {
  const int r = blockIdx.x, t = threadIdx.x;
  const float* row = h + (size_t)r * D_;
  float x0 = row[t], x1 = row[t + 128], x2 = row[t + 256];
  float s = x0 + x1 + x2;
  float q = x0 * x0 + x1 * x1 + x2 * x2;
#pragma unroll
  for (int o = 32; o; o >>= 1) {
    s += __shfl_xor(s, o);
    q += __shfl_xor(q, o);
  }
  __shared__ float rs[2], rq[2];
  if ((t & 63) == 0) { rs[t >> 6] = s; rq[t >> 6] = q; }
  __syncthreads();
  s = rs[0] + rs[1];
  q = rq[0] + rq[1];
  const float mean = s * (1.f / 384.f);
  const float var = q * (1.f / 384.f) - mean * mean;
  const float rstd = rsqrtf(var + 1e-5f);
  bf16* o = xn + (size_t)r * D_;
  o[t] = __float2bfloat16((x0 - mean) * rstd * g[t] + bt[t]);
  o[t + 128] = __float2bfloat16((x1 - mean) * rstd * g[t + 128] + bt[t + 128]);
  o[t + 256] = __float2bfloat16((x2 - mean) * rstd * g[t + 256] + bt[t + 256]);
}

// MFMA flash attention, head-major QKV input (see R12).
__global__ __launch_bounds__(256) void k_attn(const bf16* __restrict__ qkv,
                                              bf16* __restrict__ ctx) {
  const int bh = blockIdx.x;
  const int b = bh / 6, hd = bh % 6;
  const bf16* Qg = qkv + (size_t)bh * 12608;           // 197*64
  const bf16* Kg = qkv + (size_t)(768 + bh) * 12608;
  const bf16* Vg = qkv + (size_t)(1536 + bh) * 12608;
  __shared__ __align__(16) __bf16 Vt[64 * 232];
  __shared__ __align__(16) __bf16 Ps[4][16 * 232];
  const int tid = threadIdx.x;
  const int lane = tid & 63, w = tid >> 6;
  const int l16 = lane & 15, quad = lane >> 4;
  const __bf16 z = (__bf16)0.0f;

  for (int i = tid; i < 64 * 35; i += 256) {
    int d = i / 35, k = 197 + i % 35;
    Vt[d * 232 + k] = z;
  }
  for (int i = tid; i < S_ * 64; i += 256) {
    int k = i >> 6, d = i & 63;
    Vt[d * 232 + k] = *(const __bf16*)&Vg[(size_t)k * 64 + d];
  }
  for (int i = lane; i < 16 * 24; i += 64) {
    int r = i / 24, c = 208 + i % 24;
    Ps[w][r * 232 + c] = z;
  }
  __syncthreads();

  const bf16x8 zf = {};
  for (int band = w; band < 13; band += 4) {
    const int qrow = band * 16 + l16;
    bf16x8 aq0 = zf, aq1 = zf;
    if (qrow < S_) {
      aq0 = *(const bf16x8*)(Qg + (size_t)qrow * 64 + quad * 8);
      aq1 = *(const bf16x8*)(Qg + (size_t)qrow * 64 + 32 + quad * 8);
    }
    f32x4 sc[13];
#pragma unroll
    for (int t = 0; t < 13; t++) {
      const int krow = t * 16 + l16;
      bf16x8 bk0 = zf, bk1 = zf;
      if (krow < S_) {
        bk0 = *(const bf16x8*)(Kg + (size_t)krow * 64 + quad * 8);
        bk1 = *(const bf16x8*)(Kg + (size_t)krow * 64 + 32 + quad * 8);
      }
      f32x4 a = {};
      a = __builtin_amdgcn_mfma_f32_16x16x32_bf16(aq0, bk0, a, 0, 0, 0);
      a = __builtin_amdgcn_mfma_f32_16x16x32_bf16(aq1, bk1, a, 0, 0, 0);
      sc[t] = a;
    }
#pragma unroll
    for (int t = 0; t < 13; t++)
#pragma unroll
      for (int r = 0; r < 4; r++) sc[t][r] *= 0.125f;
    if (l16 >= 5) {
#pragma unroll
      for (int r = 0; r < 4; r++) sc[12][r] = -1e30f;
    }
    f32x4 mx = sc[0];
#pragma unroll
    for (int t = 1; t < 13; t++)
#pragma unroll
      for (int r = 0; r < 4; r++) mx[r] = fmaxf(mx[r], sc[t][r]);
#pragma unroll
    for (int o = 1; o < 16; o <<= 1)
#pragma unroll
      for (int r = 0; r < 4; r++) mx[r] = fmaxf(mx[r], __shfl_xor(mx[r], o));
    f32x4 sum = {};
#pragma unroll
    for (int t = 0; t < 13; t++)
#pragma unroll
      for (int r = 0; r < 4; r++) {
        float p = __expf(sc[t][r] - mx[r]);
        sc[t][r] = p;
        sum[r] += p;
      }
#pragma unroll
    for (int o = 1; o < 16; o <<= 1)
#pragma unroll
      for (int r = 0; r < 4; r++) sum[r] += __shfl_xor(sum[r], o);
    f32x4 rinv;
#pragma unroll
    for (int r = 0; r < 4; r++) rinv[r] = 1.0f / sum[r];
#pragma unroll
    for (int t = 0; t < 13; t++)
#pragma unroll
      for (int r = 0; r < 4; r++)
        Ps[w][(quad * 4 + r) * 232 + t * 16 + l16] = (__bf16)sc[t][r];
    f32x4 oacc[4] = {};
#pragma unroll
    for (int ks = 0; ks < 7; ks++) {
      bf16x8 pa = *(const bf16x8*)&Ps[w][l16 * 232 + ks * 32 + quad * 8];
#pragma unroll
      for (int c = 0; c < 4; c++) {
        bf16x8 bv = *(const bf16x8*)&Vt[(c * 16 + l16) * 232 + ks * 32 + quad * 8];
        oacc[c] = __builtin_amdgcn_mfma_f32_16x16x32_bf16(pa, bv, oacc[c], 0, 0, 0);
      }
    }
    const int orow = band * 16 + quad * 4;
#pragma unroll
    for (int c = 0; c < 4; c++)
#pragma unroll
      for (int r = 0; r < 4; r++) {
        const int rw = orow + r;
        if (rw < S_)
          ctx[((size_t)b * S_ + rw) * D_ + hd * 64 + c * 16 + l16] =
              __float2bfloat16(oacc[c][r] * rinv[r]);
      }
  }
}

__global__ __launch_bounds__(128) void k_head(const float* __restrict__ h,
                                              const float* __restrict__ g,
                                              const float* __restrict__ bt,
                                              const float* __restrict__ hw,
                                              float* __restrict__ out) {
  const int b = blockIdx.x, t = threadIdx.x;
  const float* row = h + (size_t)b * S_ * D_;
  float x0 = row[t], x1 = row[t + 128], x2 = row[t + 256];
  float s = x0 + x1 + x2;
  float q = x0 * x0 + x1 * x1 + x2 * x2;
#pragma unroll
  for (int o = 32; o; o >>= 1) {
    s += __shfl_xor(s, o);
    q += __shfl_xor(q, o);
  }
  __shared__ float rs[2], rq[2];
  if ((t & 63) == 0) { rs[t >> 6] = s; rq[t >> 6] = q; }
  __syncthreads();
  s = rs[0] + rs[1];
  q = rq[0] + rq[1];
  const float mean = s * (1.f / 384.f);
  const float var = q * (1.f / 384.f) - mean * mean;
  const float rstd = rsqrtf(var + 1e-5f);
  __shared__ float clsn[384];
  clsn[t] = (x0 - mean) * rstd * g[t] + bt[t];
  clsn[t + 128] = (x1 - mean) * rstd * g[t + 128] + bt[t + 128];
  clsn[t + 256] = (x2 - mean) * rstd * g[t + 256] + bt[t + 256];
  __syncthreads();
  if (t < 100) {
    const float* wr = hw + (size_t)t * D_;
    float a = 0.f;
    for (int d = 0; d < 384; d++) a += clsn[d] * wr[d];
    out[b * 100 + t] = a;
  }
}

extern "C" void kernel_launch(void* const* d_in, const int* in_sizes, int n_in,
                              void* d_out, int out_size, void* d_ws, size_t ws_size,
                              hipStream_t stream) {
  (void)in_sizes; (void)n_in; (void)out_size; (void)ws_size;
  const float* x       = (const float*)d_in[0];
  const float* patch_w = (const float*)d_in[1];
  const float* patch_b = (const float*)d_in[2];
  const float* cls_tok = (const float*)d_in[3];
  const float* pos_emb = (const float*)d_in[4];
  const float* ln1_g   = (const float*)d_in[5];
  const float* ln1_b   = (const float*)d_in[6];
  const float* qkv_w   = (const float*)d_in[7];
  const float* qkv_b   = (const float*)d_in[8];
  const float* out_w   = (const float*)d_in[9];
  const float* out_b   = (const float*)d_in[10];
  const float* ln2_g   = (const float*)d_in[11];
  const float* ln2_b   = (const float*)d_in[12];
  const float* fc1_w   = (const float*)d_in[13];
  const float* fc1_b   = (const float*)d_in[14];
  const float* fc2_w   = (const float*)d_in[15];
  const float* fc2_b   = (const float*)d_in[16];
  const float* lnf_g   = (const float*)d_in[17];
  const float* lnf_b   = (const float*)d_in[18];
  const float* head_w  = (const float*)d_in[19];
  float* out = (float*)d_out;

  const size_t R = (size_t)BATCH * S_;  // 25216 token rows (= 788*32)
  char* p = (char*)d_ws;
  float* h  = (float*)p; p += R * 384 * 4;       // fp32 residual
  bf16* xn  = (bf16*)p;  p += R * 384 * 2;       // LN output
  bf16* u   = (bf16*)p;  p += R * 1536 * 2;      // union: qkvb|ctxb / hid / patches
  bf16* qkvb = u;                                 // 3*768*197*64 = R*1152
  bf16* ctxb = u + R * 1152;                      // R*384
  bf16* hidb = u;                                 // R*1536 (qkv/ctx dead by then)
  bf16* patches = u;                              // 25088*768 (pre-loop only)
  bf16* wb  = (bf16*)p;                           // bf16 weights
  bf16* patch_wb = wb;                            // 768*384
  bf16* qkv_wb   = patch_wb + 294912;             // 12*1152*384
  bf16* out_wb   = qkv_wb + 5308416;              // 12*384*384
  bf16* fc1_wb   = out_wb + 1769472;              // 12*1536*384
  bf16* fc2_wb   = fc1_wb + 7077888;              // 12*384*1536

  // weight conversion fp32 -> bf16 (same work every launch; graph-safe)
  k_f2b<<<dim3((294912 / 4 + 255) / 256), dim3(256), 0, stream>>>(patch_w, patch_wb, 294912 / 4);
  k_f2b<<<dim3((5308416 / 4 + 255) / 256), dim3(256), 0, stream>>>(qkv_w, qkv_wb, 5308416 / 4);
  k_f2b<<<dim3((1769472 / 4 + 255) / 256), dim3(256), 0, stream>>>(out_w, out_wb, 1769472 / 4);
  k_f2b<<<dim3((7077888 / 4 + 255) / 256), dim3(256), 0, stream>>>(fc1_w, fc1_wb, 7077888 / 4);
  k_f2b<<<dim3((7077888 / 4 + 255) / 256), dim3(256), 0, stream>>>(fc2_w, fc2_wb, 7077888 / 4);

  k_embed_init<<<dim3((BATCH * S_ * D_) / 256), dim3(256), 0, stream>>>(cls_tok, pos_emb, h);
  k_patchify<<<dim3((BATCH * 196 * 768) / 256), dim3(256), 0, stream>>>(x, patches);
  // tok = patches @ patch_w^T + patch_b, accumulated into h (remap rows)
  k_gemm<2><<<dim3(3, 196), dim3(512), 0, stream>>>(patches, patch_wb, patch_b, nullptr, h, 384, 768, 1);

  // initial LN1 for layer 0
  k_ln<<<dim3((unsigned)R), dim3(128), 0, stream>>>(h, ln1_g, ln1_b, xn);

  for (int i = 0; i < 12; i++) {
    // qkv in head-major layout (MODE 3); reads xn
    k_gemm<3><<<dim3(9, 197), dim3(512), 0, stream>>>(xn, qkv_wb + (size_t)i * 1152 * 384,
                                                      qkv_b + i * 1152, qkvb, nullptr, 1152, 384, 0);
    k_attn<<<dim3(768), dim3(256), 0, stream>>>(qkvb, ctxb);
    // out-proj: h += ctx@W^T + b, then LN2 -> xn (for fc1)
    k_gemm_ln<<<dim3(788), dim3(256), 0, stream>>>(ctxb, out_wb + (size_t)i * 384 * 384,
                                                   out_b + i * 384, h, xn,
                                                   ln2_g + i * 384, ln2_b + i * 384, 384);
    // fc1 reads xn
    k_gemm<1><<<dim3(12, 197), dim3(512), 0, stream>>>(xn, fc1_wb + (size_t)i * 1536 * 384,
                                                       fc1_b + i * 1536, hidb, nullptr, 1536, 384, 0);
    // fc2: h += hid@W^T + b, then LN1 of next layer -> xn (unused for i=11)
    const int nx = (i + 1) % 12;
    k_gemm_ln<<<dim3(788), dim3(256), 0, stream>>>(hidb, fc2_wb + (size_t)i * 384 * 1536,
                                                   fc2_b + i * 384, h, xn,
                                                   ln1_g + nx * 384, ln1_b + nx * 384, 1536);
  }
  k_head<<<dim3(128), dim3(128), 0, stream>>>(h, lnf_g, lnf_b, head_w, out);
}

// Round 10
// 3551.516 us; speedup vs baseline: 1.0546x; 1.0546x over previous
//
#include <hip/hip_runtime.h>
#include <hip/hip_bf16.h>

// ViT-S/16 forward, B=128. Inputs/outputs fp32 (per reference). Internal:
// weights+activations bf16 for MFMA, residual stream fp32, LN/softmax fp32.
// R11: XCD-aware bijective block swizzle (T1/m204). R12: gelu tanh + head-
// major QKV. R13: 8-wave 512-thread GEMM blocks (3228 us).
// R14 (k_gemm_ln BM=32xBN=384) regressed (2 blocks/CU) -> reverted.
// R15: slim k_attn. Old: Vt 29.7KB + full per-wave Ps 29.7KB = 59KB LDS ->
// 2 blocks/CU, Occ 9.6%, all pipes idle (latency-bound). New: PV consumes P
// in 32-key slices, so the C->A transpose round-trip uses a tiny per-wave
// Ps[16][40] slice written/read per ks step (same-wave in-order DS ops, no
// barrier needed -- same pattern as before). LDS 59 -> 34.8KB -> 4 blocks/CU;
// launch_bounds(256,4) caps VGPR at 128 so VGPR doesn't bind.

#define S_ 197
#define D_ 384
#define BATCH 128

using bf16 = __hip_bfloat16;
typedef __attribute__((ext_vector_type(8))) __bf16 bf16x8;
typedef __attribute__((ext_vector_type(4))) float f32x4;

#if __has_builtin(__builtin_amdgcn_global_load_lds)
#define HAVE_GLL 1
__device__ __forceinline__ void gll16(const bf16* g, __bf16* l) {
  __builtin_amdgcn_global_load_lds(
      (const __attribute__((address_space(1))) void*)g,
      (__attribute__((address_space(3))) void*)l, 16, 0, 0);
}
#else
#define HAVE_GLL 0
#endif

// fp32 -> bf16 (RN), 4 elements/thread. n must be a multiple of 4.
__global__ __launch_bounds__(256) void k_f2b(const float* __restrict__ src,
                                             bf16* __restrict__ dst, int n4) {
  int i = blockIdx.x * 256 + threadIdx.x;
  if (i >= n4) return;
  float4 v = ((const float4*)src)[i];
  bf16 o[4] = {__float2bfloat16(v.x), __float2bfloat16(v.y),
               __float2bfloat16(v.z), __float2bfloat16(v.w)};
  ((uint2*)dst)[i] = *(uint2*)o;
}

__global__ __launch_bounds__(256) void k_embed_init(const float* __restrict__ cls,
                                                    const float* __restrict__ pos,
                                                    float* __restrict__ h) {
  int idx = blockIdx.x * 256 + threadIdx.x;
  if (idx >= BATCH * S_ * D_) return;
  int d = idx % D_;
  int s = (idx / D_) % S_;
  float v = pos[s * D_ + d];
  if (s == 0) v += cls[d];
  h[idx] = v;
}

__global__ __launch_bounds__(256) void k_patchify(const float* __restrict__ x,
                                                  bf16* __restrict__ patches) {
  int idx = blockIdx.x * 256 + threadIdx.x;
  if (idx >= BATCH * 196 * 768) return;
  int f = idx % 768;
  int n = (idx / 768) % 196;
  int b = idx / (768 * 196);
  int c = f >> 8, rem = f & 255, dy = rem >> 4, dx = rem & 15;
  int py = n / 14, px = n % 14;
  patches[idx] = __float2bfloat16(
      x[(((size_t)b * 3 + c) * 224 + py * 16 + dy) * 224 + px * 16 + dx]);
}

// out[M,N] = X[M,K] @ W[N,K]^T + bias.  Grid: (N/128, M/128), 512 threads.
// 8 waves in 2x4: wave tile 64 rows x 32 cols, acc[4][2].
// MODE 0: out=bf16(v); MODE 1: out=bf16(gelu_tanh(v));
// MODE 2: res(f32)+=v (remap!=0: row r -> r + r/196 + 1)
// MODE 3: out=bf16(v) head-major QKV.
template <int MODE>
__global__ __launch_bounds__(512, 6) void k_gemm(const bf16* __restrict__ X,
                                                 const bf16* __restrict__ W,
                                                 const float* __restrict__ bias,
                                                 bf16* __restrict__ out,
                                                 float* __restrict__ res,
                                                 int N, int K, int remap) {
  __shared__ __align__(16) __bf16 As[2][128 * 32];
  __shared__ __align__(16) __bf16 Bs[2][128 * 32];
  const int tid = threadIdx.x;

  // XCD-aware bijective swizzle (T1/m204)
  const int gx = gridDim.x;
  const int nwg = gx * gridDim.y;
  const int lid = blockIdx.y * gx + blockIdx.x;
  const int xcd = lid & 7, sseq = lid >> 3;
  const int q8 = nwg >> 3, r8 = nwg & 7;
  const int start = xcd * q8 + (xcd < r8 ? xcd : r8);
  const int wgid = start + sseq;
  const int m0 = (wgid / gx) * 128, n0 = (wgid % gx) * 128;

  const int lane = tid & 63, w = tid >> 6;     // w in 0..7
  const int wr = w >> 2, wc = w & 3;           // 2x4 wave grid
  const int l16 = lane & 15, quad = lane >> 4;
  f32x4 acc[4][2] = {};

  const int srow = w * 16 + (lane >> 2);
  const int scol = (((lane & 3) ^ ((lane >> 3) & 3)) << 3);
  const bf16* Ag = X + (size_t)(m0 + srow) * K + scol;
  const bf16* Bg = W + (size_t)(n0 + srow) * K + scol;
  const int ldsW = w * 512;

  const int jx8 = ((quad ^ ((l16 >> 1) & 3)) << 3);
  const int aoff = (wr * 64 + l16) * 32 + jx8;
  const int boff = (wc * 32 + l16) * 32 + jx8;

#if HAVE_GLL
#define STAGE(buf, k0)                 \
  do {                                 \
    gll16(Ag + (k0), &As[buf][ldsW]);  \
    gll16(Bg + (k0), &Bs[buf][ldsW]);  \
  } while (0)
#else
#define STAGE(buf, k0)                                                \
  do {                                                                \
    *(uint4*)(&As[buf][ldsW + (lane >> 2) * 32 + (lane & 3) * 8]) =   \
        *(const uint4*)(Ag + (k0));                                   \
    *(uint4*)(&Bs[buf][ldsW + (lane >> 2) * 32 + (lane & 3) * 8]) =   \
        *(const uint4*)(Bg + (k0));                                   \
  } while (0)
#endif

  STAGE(0, 0);
  __syncthreads();
  for (int k0 = 0; k0 < K; k0 += 32) {
    const int cb = (k0 >> 5) & 1;
    if (k0 + 32 < K) STAGE(cb ^ 1, k0 + 32);
    bf16x8 av[4], bv[2];
#pragma unroll
    for (int i = 0; i < 4; i++)
      av[i] = *(const bf16x8*)(&As[cb][aoff + i * 512]);
#pragma unroll
    for (int j = 0; j < 2; j++)
      bv[j] = *(const bf16x8*)(&Bs[cb][boff + j * 512]);
#pragma unroll
    for (int i = 0; i < 4; i++)
#pragma unroll
      for (int j = 0; j < 2; j++)
        acc[i][j] = __builtin_amdgcn_mfma_f32_16x16x32_bf16(av[i], bv[j], acc[i][j], 0, 0, 0);
    __syncthreads();
  }
#undef STAGE

  float bvv[2];
#pragma unroll
  for (int j = 0; j < 2; j++)
    bvv[j] = bias[n0 + wc * 32 + j * 16 + l16];
#pragma unroll
  for (int i = 0; i < 4; i++) {
    const int rbase = m0 + wr * 64 + i * 16 + quad * 4;
#pragma unroll
    for (int j = 0; j < 2; j++) {
      const int col = n0 + wc * 32 + j * 16 + l16;
      const int which = col / 384;
      const int hd2 = (col >> 6) % 6;
      const int d = col & 63;
#pragma unroll
      for (int r = 0; r < 4; r++) {
        float v = acc[i][j][r] + bvv[j];
        int rw = rbase + r;
        if (MODE == 0) {
          out[(size_t)rw * N + col] = __float2bfloat16(v);
        } else if (MODE == 1) {
          float t = 0.7978845608f * v * (1.f + 0.044715f * v * v);
          float e = __expf(2.f * t);
          float th = 1.f - 2.f / (e + 1.f);
          out[(size_t)rw * N + col] = __float2bfloat16(0.5f * v * (1.f + th));
        } else if (MODE == 3) {
          int b2 = rw / 197;
          int s = rw - b2 * 197;
          out[((size_t)(which * 768 + b2 * 6 + hd2) * 197 + s) * 64 + d] =
              __float2bfloat16(v);
        } else {
          int hr = remap ? (rw + rw / 196 + 1) : rw;
          res[(size_t)hr * N + col] += v;
        }
      }
    }
  }
}

__global__ __launch_bounds__(128) void k_ln(const float* __restrict__ h,
                                            const float* __restrict__ g,
                                            const float* __restrict__ bt,
                                            bf16* __restrict__ xn) {
  const int r = blockIdx.x, t = threadIdx.x;
  const float* row = h + (size_t)r * D_;
  float x0 = row[t], x1 = row[t + 128], x2 = row[t + 256];
  float s = x0 + x1 + x2;
  float q = x0 * x0 + x1 * x1 + x2 * x2;
#pragma unroll
  for (int o = 32; o; o >>= 1) {
    s += __shfl_xor(s, o);
    q += __shfl_xor(q, o);
  }
  __shared__ float rs[2], rq[2];
  if ((t & 63) == 0) { rs[t >> 6] = s; rq[t >> 6] = q; }
  __syncthreads();
  s = rs[0] + rs[1];
  q = rq[0] + rq[1];
  const float mean = s * (1.f / 384.f);
  const float var = q * (1.f / 384.f) - mean * mean;
  const float rstd = rsqrtf(var + 1e-5f);
  bf16* o = xn + (size_t)r * D_;
  o[t] = __float2bfloat16((x0 - mean) * rstd * g[t] + bt[t]);
  o[t + 128] = __float2bfloat16((x1 - mean) * rstd * g[t + 128] + bt[t + 128]);
  o[t + 256] = __float2bfloat16((x2 - mean) * rstd * g[t + 256] + bt[t + 256]);
}

// MFMA flash attention, head-major QKV input: Q/K/V each [197][64] contiguous
// per (b,head). One block per (b, head), 4 waves; wave owns q-bands
// {w, w+4, ...}: QK^T (13 col-tiles) -> masked softmax -> per-32-key P slice
// to LDS -> PV MFMA (interleaved; same-wave in-order DS ops, no barrier).
__global__ __launch_bounds__(256, 4) void k_attn(const bf16* __restrict__ qkv,
                                                 bf16* __restrict__ ctx) {
  const int bh = blockIdx.x;
  const int b = bh / 6, hd = bh % 6;
  const bf16* Qg = qkv + (size_t)bh * 12608;           // 197*64
  const bf16* Kg = qkv + (size_t)(768 + bh) * 12608;
  const bf16* Vg = qkv + (size_t)(1536 + bh) * 12608;
  // Vt[d][k] = V[k][d]; stride 232 (2-way b128 read alias = free)
  __shared__ __align__(16) __bf16 Vt[64 * 232];
  // per-wave 32-key P slice: [16 q-rows][40] (cols 0..31 used; stride 40
  // elems = 20 dw -> quad pairs 2-way alias on write/read = free)
  __shared__ __align__(16) __bf16 Ps[4][16 * 40];
  const int tid = threadIdx.x;
  const int lane = tid & 63, w = tid >> 6;
  const int l16 = lane & 15, quad = lane >> 4;
  const __bf16 z = (__bf16)0.0f;

  // zero Vt pad cols (k = 197..231)
  for (int i = tid; i < 64 * 35; i += 256) {
    int d = i / 35, k = 197 + i % 35;
    Vt[d * 232 + k] = z;
  }
  // stage V transposed (global reads are 128-B contiguous rows)
  for (int i = tid; i < S_ * 64; i += 256) {
    int k = i >> 6, d = i & 63;
    Vt[d * 232 + k] = *(const __bf16*)&Vg[(size_t)k * 64 + d];
  }
  __syncthreads();

  const bf16x8 zf = {};
  for (int band = w; band < 13; band += 4) {
    // Q A-fragments (row = band*16 + l16), predicated on row < 197
    const int qrow = band * 16 + l16;
    bf16x8 aq0 = zf, aq1 = zf;
    if (qrow < S_) {
      aq0 = *(const bf16x8*)(Qg + (size_t)qrow * 64 + quad * 8);
      aq1 = *(const bf16x8*)(Qg + (size_t)qrow * 64 + 32 + quad * 8);
    }
    // scores: 13 col-tiles of 16
    f32x4 sc[13];
#pragma unroll
    for (int t = 0; t < 13; t++) {
      const int krow = t * 16 + l16;
      bf16x8 bk0 = zf, bk1 = zf;
      if (krow < S_) {
        bk0 = *(const bf16x8*)(Kg + (size_t)krow * 64 + quad * 8);
        bk1 = *(const bf16x8*)(Kg + (size_t)krow * 64 + 32 + quad * 8);
      }
      f32x4 a = {};
      a = __builtin_amdgcn_mfma_f32_16x16x32_bf16(aq0, bk0, a, 0, 0, 0);
      a = __builtin_amdgcn_mfma_f32_16x16x32_bf16(aq1, bk1, a, 0, 0, 0);
      sc[t] = a;
    }
    // scale 1/sqrt(64), mask pad cols (tile 12: keys 192+l16 >= 197)
#pragma unroll
    for (int t = 0; t < 13; t++)
#pragma unroll
      for (int r = 0; r < 4; r++) sc[t][r] *= 0.125f;
    if (l16 >= 5) {
#pragma unroll
      for (int r = 0; r < 4; r++) sc[12][r] = -1e30f;
    }
    // row max (13 tiles in-reg, then across the 16 lanes of this quad)
    f32x4 mx = sc[0];
#pragma unroll
    for (int t = 1; t < 13; t++)
#pragma unroll
      for (int r = 0; r < 4; r++) mx[r] = fmaxf(mx[r], sc[t][r]);
#pragma unroll
    for (int o = 1; o < 16; o <<= 1)
#pragma unroll
      for (int r = 0; r < 4; r++) mx[r] = fmaxf(mx[r], __shfl_xor(mx[r], o));
    // exp + row sum
    f32x4 sum = {};
#pragma unroll
    for (int t = 0; t < 13; t++)
#pragma unroll
      for (int r = 0; r < 4; r++) {
        float p = __expf(sc[t][r] - mx[r]);
        sc[t][r] = p;
        sum[r] += p;
      }
#pragma unroll
    for (int o = 1; o < 16; o <<= 1)
#pragma unroll
      for (int r = 0; r < 4; r++) sum[r] += __shfl_xor(sum[r], o);
    f32x4 rinv;
#pragma unroll
    for (int r = 0; r < 4; r++) rinv[r] = 1.0f / sum[r];
    // P @ V in 32-key slices: write slice (C layout), read pa (A layout),
    // 4 MFMA. Same-wave DS ops execute in order -> no barrier needed.
    f32x4 oacc[4] = {};
#pragma unroll
    for (int ks = 0; ks < 7; ks++) {
#pragma unroll
      for (int tt = 0; tt < 2; tt++) {
        const int t = ks * 2 + tt;
#pragma unroll
        for (int r = 0; r < 4; r++)
          Ps[w][(quad * 4 + r) * 40 + tt * 16 + l16] =
              (t < 13) ? (__bf16)sc[t][r] : z;
      }
      bf16x8 pa = *(const bf16x8*)&Ps[w][l16 * 40 + quad * 8];
#pragma unroll
      for (int c = 0; c < 4; c++) {
        bf16x8 bv = *(const bf16x8*)&Vt[(c * 16 + l16) * 232 + ks * 32 + quad * 8];
        oacc[c] = __builtin_amdgcn_mfma_f32_16x16x32_bf16(pa, bv, oacc[c], 0, 0, 0);
      }
    }
    // epilogue: rows band*16 + quad*4 + r (guarded), cols hd*64 + c*16 + l16
    const int orow = band * 16 + quad * 4;
#pragma unroll
    for (int c = 0; c < 4; c++)
#pragma unroll
      for (int r = 0; r < 4; r++) {
        const int rw = orow + r;
        if (rw < S_)
          ctx[((size_t)b * S_ + rw) * D_ + hd * 64 + c * 16 + l16] =
              __float2bfloat16(oacc[c][r] * rinv[r]);
      }
  }
}

__global__ __launch_bounds__(128) void k_head(const float* __restrict__ h,
                                              const float* __restrict__ g,
                                              const float* __restrict__ bt,
                                              const float* __restrict__ hw,
                                              float* __restrict__ out) {
  const int b = blockIdx.x, t = threadIdx.x;
  const float* row = h + (size_t)b * S_ * D_;
  float x0 = row[t], x1 = row[t + 128], x2 = row[t + 256];
  float s = x0 + x1 + x2;
  float q = x0 * x0 + x1 * x1 + x2 * x2;
#pragma unroll
  for (int o = 32; o; o >>= 1) {
    s += __shfl_xor(s, o);
    q += __shfl_xor(q, o);
  }
  __shared__ float rs[2], rq[2];
  if ((t & 63) == 0) { rs[t >> 6] = s; rq[t >> 6] = q; }
  __syncthreads();
  s = rs[0] + rs[1];
  q = rq[0] + rq[1];
  const float mean = s * (1.f / 384.f);
  const float var = q * (1.f / 384.f) - mean * mean;
  const float rstd = rsqrtf(var + 1e-5f);
  __shared__ float clsn[384];
  clsn[t] = (x0 - mean) * rstd * g[t] + bt[t];
  clsn[t + 128] = (x1 - mean) * rstd * g[t + 128] + bt[t + 128];
  clsn[t + 256] = (x2 - mean) * rstd * g[t + 256] + bt[t + 256];
  __syncthreads();
  if (t < 100) {
    const float* wr = hw + (size_t)t * D_;
    float a = 0.f;
    for (int d = 0; d < 384; d++) a += clsn[d] * wr[d];
    out[b * 100 + t] = a;
  }
}

extern "C" void kernel_launch(void* const* d_in, const int* in_sizes, int n_in,
                              void* d_out, int out_size, void* d_ws, size_t ws_size,
                              hipStream_t stream) {
  (void)in_sizes; (void)n_in; (void)out_size; (void)ws_size;
  const float* x       = (const float*)d_in[0];
  const float* patch_w = (const float*)d_in[1];
  const float* patch_b = (const float*)d_in[2];
  const float* cls_tok = (const float*)d_in[3];
  const float* pos_emb = (const float*)d_in[4];
  const float* ln1_g   = (const float*)d_in[5];
  const float* ln1_b   = (const float*)d_in[6];
  const float* qkv_w   = (const float*)d_in[7];
  const float* qkv_b   = (const float*)d_in[8];
  const float* out_w   = (const float*)d_in[9];
  const float* out_b   = (const float*)d_in[10];
  const float* ln2_g   = (const float*)d_in[11];
  const float* ln2_b   = (const float*)d_in[12];
  const float* fc1_w   = (const float*)d_in[13];
  const float* fc1_b   = (const float*)d_in[14];
  const float* fc2_w   = (const float*)d_in[15];
  const float* fc2_b   = (const float*)d_in[16];
  const float* lnf_g   = (const float*)d_in[17];
  const float* lnf_b   = (const float*)d_in[18];
  const float* head_w  = (const float*)d_in[19];
  float* out = (float*)d_out;

  const size_t R = (size_t)BATCH * S_;  // 25216 token rows
  char* p = (char*)d_ws;
  float* h  = (float*)p; p += R * 384 * 4;       // fp32 residual
  bf16* xn  = (bf16*)p;  p += R * 384 * 2;       // LN output
  bf16* u   = (bf16*)p;  p += R * 1536 * 2;      // union: qkvb|ctxb / hid / patches
  bf16* qkvb = u;                                 // 3*768*197*64 = R*1152
  bf16* ctxb = u + R * 1152;                      // R*384
  bf16* hidb = u;                                 // R*1536 (qkv/ctx dead by then)
  bf16* patches = u;                              // 25088*768 (pre-loop only)
  bf16* wb  = (bf16*)p;                           // bf16 weights
  bf16* patch_wb = wb;                            // 768*384
  bf16* qkv_wb   = patch_wb + 294912;             // 12*1152*384
  bf16* out_wb   = qkv_wb + 5308416;              // 12*384*384
  bf16* fc1_wb   = out_wb + 1769472;              // 12*1536*384
  bf16* fc2_wb   = fc1_wb + 7077888;              // 12*384*1536

  // weight conversion fp32 -> bf16 (same work every launch; graph-safe)
  k_f2b<<<dim3((294912 / 4 + 255) / 256), dim3(256), 0, stream>>>(patch_w, patch_wb, 294912 / 4);
  k_f2b<<<dim3((5308416 / 4 + 255) / 256), dim3(256), 0, stream>>>(qkv_w, qkv_wb, 5308416 / 4);
  k_f2b<<<dim3((1769472 / 4 + 255) / 256), dim3(256), 0, stream>>>(out_w, out_wb, 1769472 / 4);
  k_f2b<<<dim3((7077888 / 4 + 255) / 256), dim3(256), 0, stream>>>(fc1_w, fc1_wb, 7077888 / 4);
  k_f2b<<<dim3((7077888 / 4 + 255) / 256), dim3(256), 0, stream>>>(fc2_w, fc2_wb, 7077888 / 4);

  k_embed_init<<<dim3((BATCH * S_ * D_) / 256), dim3(256), 0, stream>>>(cls_tok, pos_emb, h);
  k_patchify<<<dim3((BATCH * 196 * 768) / 256), dim3(256), 0, stream>>>(x, patches);
  // tok = patches @ patch_w^T + patch_b, accumulated into h (remap rows)
  k_gemm<2><<<dim3(3, 196), dim3(512), 0, stream>>>(patches, patch_wb, patch_b, nullptr, h, 384, 768, 1);

  for (int i = 0; i < 12; i++) {
    k_ln<<<dim3((unsigned)R), dim3(128), 0, stream>>>(h, ln1_g + i * 384, ln1_b + i * 384, xn);
    // qkv in head-major layout (MODE 3)
    k_gemm<3><<<dim3(9, 197), dim3(512), 0, stream>>>(xn, qkv_wb + (size_t)i * 1152 * 384,
                                                      qkv_b + i * 1152, qkvb, nullptr, 1152, 384, 0);
    k_attn<<<dim3(768), dim3(256), 0, stream>>>(qkvb, ctxb);
    k_gemm<2><<<dim3(3, 197), dim3(512), 0, stream>>>(ctxb, out_wb + (size_t)i * 384 * 384,
                                                      out_b + i * 384, nullptr, h, 384, 384, 0);
    k_ln<<<dim3((unsigned)R), dim3(128), 0, stream>>>(h, ln2_g + i * 384, ln2_b + i * 384, xn);
    k_gemm<1><<<dim3(12, 197), dim3(512), 0, stream>>>(xn, fc1_wb + (size_t)i * 1536 * 384,
                                                       fc1_b + i * 1536, hidb, nullptr, 1536, 384, 0);
    k_gemm<2><<<dim3(3, 197), dim3(512), 0, stream>>>(hidb, fc2_wb + (size_t)i * 384 * 1536,
                                                      fc2_b + i * 384, nullptr, h, 384, 1536, 0);
  }
  k_head<<<dim3(128), dim3(128), 0, stream>>>(h, lnf_g, lnf_b, head_w, out);
}

// Round 11
// 3099.185 us; speedup vs baseline: 1.2085x; 1.1460x over previous
//
#include <hip/hip_runtime.h>
#include <hip/hip_bf16.h>

// ViT-S/16 forward, B=128. Inputs/outputs fp32 (per reference). Internal:
// weights+activations bf16 for MFMA, residual stream fp32, LN/softmax fp32.
// R11: XCD-aware bijective block swizzle (T1/m204). R12: gelu tanh + head-
// major QKV. R13: 8-wave 512-thread GEMM blocks (3228 us).
// R15 post-mortem: Ps-slice raised attn occupancy 2->4 blocks/CU, but each
// block re-reads K from GLOBAL once per band (13x) -> per-XCD L2 working set
// doubled -> thrash: FETCH 28->142 MB, total regressed. R16: stage K in LDS
// once per block (rows 197..207 zeroed, stride 72 = 2-way b128 alias); QK^T
// reads K from LDS. Keep the small Ps slice (correctness validated in R15).
// LDS = Vt 29.7K + Ks 29.9K + Ps 5.1K = 64.8K -> 2 blocks/CU (same residency
// as R13, no thrash) with the 13x global K re-read latency+traffic gone.

#define S_ 197
#define D_ 384
#define BATCH 128

using bf16 = __hip_bfloat16;
typedef __attribute__((ext_vector_type(8))) __bf16 bf16x8;
typedef __attribute__((ext_vector_type(4))) float f32x4;

#if __has_builtin(__builtin_amdgcn_global_load_lds)
#define HAVE_GLL 1
__device__ __forceinline__ void gll16(const bf16* g, __bf16* l) {
  __builtin_amdgcn_global_load_lds(
      (const __attribute__((address_space(1))) void*)g,
      (__attribute__((address_space(3))) void*)l, 16, 0, 0);
}
#else
#define HAVE_GLL 0
#endif

// fp32 -> bf16 (RN), 4 elements/thread. n must be a multiple of 4.
__global__ __launch_bounds__(256) void k_f2b(const float* __restrict__ src,
                                             bf16* __restrict__ dst, int n4) {
  int i = blockIdx.x * 256 + threadIdx.x;
  if (i >= n4) return;
  float4 v = ((const float4*)src)[i];
  bf16 o[4] = {__float2bfloat16(v.x), __float2bfloat16(v.y),
               __float2bfloat16(v.z), __float2bfloat16(v.w)};
  ((uint2*)dst)[i] = *(uint2*)o;
}

__global__ __launch_bounds__(256) void k_embed_init(const float* __restrict__ cls,
                                                    const float* __restrict__ pos,
                                                    float* __restrict__ h) {
  int idx = blockIdx.x * 256 + threadIdx.x;
  if (idx >= BATCH * S_ * D_) return;
  int d = idx % D_;
  int s = (idx / D_) % S_;
  float v = pos[s * D_ + d];
  if (s == 0) v += cls[d];
  h[idx] = v;
}

__global__ __launch_bounds__(256) void k_patchify(const float* __restrict__ x,
                                                  bf16* __restrict__ patches) {
  int idx = blockIdx.x * 256 + threadIdx.x;
  if (idx >= BATCH * 196 * 768) return;
  int f = idx % 768;
  int n = (idx / 768) % 196;
  int b = idx / (768 * 196);
  int c = f >> 8, rem = f & 255, dy = rem >> 4, dx = rem & 15;
  int py = n / 14, px = n % 14;
  patches[idx] = __float2bfloat16(
      x[(((size_t)b * 3 + c) * 224 + py * 16 + dy) * 224 + px * 16 + dx]);
}

// out[M,N] = X[M,K] @ W[N,K]^T + bias.  Grid: (N/128, M/128), 512 threads.
// 8 waves in 2x4: wave tile 64 rows x 32 cols, acc[4][2].
// MODE 0: out=bf16(v); MODE 1: out=bf16(gelu_tanh(v));
// MODE 2: res(f32)+=v (remap!=0: row r -> r + r/196 + 1)
// MODE 3: out=bf16(v) head-major QKV.
template <int MODE>
__global__ __launch_bounds__(512, 6) void k_gemm(const bf16* __restrict__ X,
                                                 const bf16* __restrict__ W,
                                                 const float* __restrict__ bias,
                                                 bf16* __restrict__ out,
                                                 float* __restrict__ res,
                                                 int N, int K, int remap) {
  __shared__ __align__(16) __bf16 As[2][128 * 32];
  __shared__ __align__(16) __bf16 Bs[2][128 * 32];
  const int tid = threadIdx.x;

  // XCD-aware bijective swizzle (T1/m204)
  const int gx = gridDim.x;
  const int nwg = gx * gridDim.y;
  const int lid = blockIdx.y * gx + blockIdx.x;
  const int xcd = lid & 7, sseq = lid >> 3;
  const int q8 = nwg >> 3, r8 = nwg & 7;
  const int start = xcd * q8 + (xcd < r8 ? xcd : r8);
  const int wgid = start + sseq;
  const int m0 = (wgid / gx) * 128, n0 = (wgid % gx) * 128;

  const int lane = tid & 63, w = tid >> 6;     // w in 0..7
  const int wr = w >> 2, wc = w & 3;           // 2x4 wave grid
  const int l16 = lane & 15, quad = lane >> 4;
  f32x4 acc[4][2] = {};

  const int srow = w * 16 + (lane >> 2);
  const int scol = (((lane & 3) ^ ((lane >> 3) & 3)) << 3);
  const bf16* Ag = X + (size_t)(m0 + srow) * K + scol;
  const bf16* Bg = W + (size_t)(n0 + srow) * K + scol;
  const int ldsW = w * 512;

  const int jx8 = ((quad ^ ((l16 >> 1) & 3)) << 3);
  const int aoff = (wr * 64 + l16) * 32 + jx8;
  const int boff = (wc * 32 + l16) * 32 + jx8;

#if HAVE_GLL
#define STAGE(buf, k0)                 \
  do {                                 \
    gll16(Ag + (k0), &As[buf][ldsW]);  \
    gll16(Bg + (k0), &Bs[buf][ldsW]);  \
  } while (0)
#else
#define STAGE(buf, k0)                                                \
  do {                                                                \
    *(uint4*)(&As[buf][ldsW + (lane >> 2) * 32 + (lane & 3) * 8]) =   \
        *(const uint4*)(Ag + (k0));                                   \
    *(uint4*)(&Bs[buf][ldsW + (lane >> 2) * 32 + (lane & 3) * 8]) =   \
        *(const uint4*)(Bg + (k0));                                   \
  } while (0)
#endif

  STAGE(0, 0);
  __syncthreads();
  for (int k0 = 0; k0 < K; k0 += 32) {
    const int cb = (k0 >> 5) & 1;
    if (k0 + 32 < K) STAGE(cb ^ 1, k0 + 32);
    bf16x8 av[4], bv[2];
#pragma unroll
    for (int i = 0; i < 4; i++)
      av[i] = *(const bf16x8*)(&As[cb][aoff + i * 512]);
#pragma unroll
    for (int j = 0; j < 2; j++)
      bv[j] = *(const bf16x8*)(&Bs[cb][boff + j * 512]);
#pragma unroll
    for (int i = 0; i < 4; i++)
#pragma unroll
      for (int j = 0; j < 2; j++)
        acc[i][j] = __builtin_amdgcn_mfma_f32_16x16x32_bf16(av[i], bv[j], acc[i][j], 0, 0, 0);
    __syncthreads();
  }
#undef STAGE

  float bvv[2];
#pragma unroll
  for (int j = 0; j < 2; j++)
    bvv[j] = bias[n0 + wc * 32 + j * 16 + l16];
#pragma unroll
  for (int i = 0; i < 4; i++) {
    const int rbase = m0 + wr * 64 + i * 16 + quad * 4;
#pragma unroll
    for (int j = 0; j < 2; j++) {
      const int col = n0 + wc * 32 + j * 16 + l16;
      const int which = col / 384;
      const int hd2 = (col >> 6) % 6;
      const int d = col & 63;
#pragma unroll
      for (int r = 0; r < 4; r++) {
        float v = acc[i][j][r] + bvv[j];
        int rw = rbase + r;
        if (MODE == 0) {
          out[(size_t)rw * N + col] = __float2bfloat16(v);
        } else if (MODE == 1) {
          float t = 0.7978845608f * v * (1.f + 0.044715f * v * v);
          float e = __expf(2.f * t);
          float th = 1.f - 2.f / (e + 1.f);
          out[(size_t)rw * N + col] = __float2bfloat16(0.5f * v * (1.f + th));
        } else if (MODE == 3) {
          int b2 = rw / 197;
          int s = rw - b2 * 197;
          out[((size_t)(which * 768 + b2 * 6 + hd2) * 197 + s) * 64 + d] =
              __float2bfloat16(v);
        } else {
          int hr = remap ? (rw + rw / 196 + 1) : rw;
          res[(size_t)hr * N + col] += v;
        }
      }
    }
  }
}

__global__ __launch_bounds__(128) void k_ln(const float* __restrict__ h,
                                            const float* __restrict__ g,
                                            const float* __restrict__ bt,
                                            bf16* __restrict__ xn) {
  const int r = blockIdx.x, t = threadIdx.x;
  const float* row = h + (size_t)r * D_;
  float x0 = row[t], x1 = row[t + 128], x2 = row[t + 256];
  float s = x0 + x1 + x2;
  float q = x0 * x0 + x1 * x1 + x2 * x2;
#pragma unroll
  for (int o = 32; o; o >>= 1) {
    s += __shfl_xor(s, o);
    q += __shfl_xor(q, o);
  }
  __shared__ float rs[2], rq[2];
  if ((t & 63) == 0) { rs[t >> 6] = s; rq[t >> 6] = q; }
  __syncthreads();
  s = rs[0] + rs[1];
  q = rq[0] + rq[1];
  const float mean = s * (1.f / 384.f);
  const float var = q * (1.f / 384.f) - mean * mean;
  const float rstd = rsqrtf(var + 1e-5f);
  bf16* o = xn + (size_t)r * D_;
  o[t] = __float2bfloat16((x0 - mean) * rstd * g[t] + bt[t]);
  o[t + 128] = __float2bfloat16((x1 - mean) * rstd * g[t + 128] + bt[t + 128]);
  o[t + 256] = __float2bfloat16((x2 - mean) * rstd * g[t + 256] + bt[t + 256]);
}

// MFMA flash attention, head-major QKV input: Q/K/V each [197][64] contiguous
// per (b,head). One block per (b, head), 4 waves; wave owns q-bands
// {w, w+4, ...}. K and V staged in LDS once per block (K rows 197..207
// zeroed so QK needs no guard; zero K rows give score 0, masked for tile 12
// cols >= 197 exactly as before). QK^T from LDS -> masked softmax ->
// per-32-key P slice -> PV MFMA (same-wave in-order DS ops, no barrier).
__global__ __launch_bounds__(256, 2) void k_attn(const bf16* __restrict__ qkv,
                                                 bf16* __restrict__ ctx) {
  const int bh = blockIdx.x;
  const int b = bh / 6, hd = bh % 6;
  const bf16* Qg = qkv + (size_t)bh * 12608;           // 197*64
  const bf16* Kg = qkv + (size_t)(768 + bh) * 12608;
  const bf16* Vg = qkv + (size_t)(1536 + bh) * 12608;
  // Vt[d][k] = V[k][d]; stride 232 (2-way b128 read alias = free)
  __shared__ __align__(16) __bf16 Vt[64 * 232];
  // Ks[k][d]; stride 72 -> b128 reads 2-way bank alias (free)
  __shared__ __align__(16) __bf16 Ks[208 * 72];
  // per-wave 32-key P slice: [16 q-rows][40]
  __shared__ __align__(16) __bf16 Ps[4][16 * 40];
  const int tid = threadIdx.x;
  const int lane = tid & 63, w = tid >> 6;
  const int l16 = lane & 15, quad = lane >> 4;
  const __bf16 z = (__bf16)0.0f;

  // zero Vt pad cols (k = 197..231)
  for (int i = tid; i < 64 * 35; i += 256) {
    int d = i / 35, k = 197 + i % 35;
    Vt[d * 232 + k] = z;
  }
  // stage V transposed (global reads are 128-B contiguous rows)
  for (int i = tid; i < S_ * 64; i += 256) {
    int k = i >> 6, d = i & 63;
    Vt[d * 232 + k] = *(const __bf16*)&Vg[(size_t)k * 64 + d];
  }
  // stage K row-major (8B per thread), zero pad rows 197..207
  for (int i = tid; i < 208 * 16; i += 256) {
    int r = i >> 4, c = (i & 15) * 4;
    uint2 v = {0u, 0u};
    if (r < S_) v = *(const uint2*)&Kg[(size_t)r * 64 + c];
    *(uint2*)&Ks[r * 72 + c] = v;
  }
  __syncthreads();

  const bf16x8 zf = {};
  for (int band = w; band < 13; band += 4) {
    // Q A-fragments (row = band*16 + l16), predicated on row < 197
    const int qrow = band * 16 + l16;
    bf16x8 aq0 = zf, aq1 = zf;
    if (qrow < S_) {
      aq0 = *(const bf16x8*)(Qg + (size_t)qrow * 64 + quad * 8);
      aq1 = *(const bf16x8*)(Qg + (size_t)qrow * 64 + 32 + quad * 8);
    }
    // scores: 13 col-tiles of 16, K from LDS (pad rows are zeros)
    f32x4 sc[13];
#pragma unroll
    for (int t = 0; t < 13; t++) {
      const int krow = t * 16 + l16;  // <= 207, always in-bounds
      bf16x8 bk0 = *(const bf16x8*)&Ks[krow * 72 + quad * 8];
      bf16x8 bk1 = *(const bf16x8*)&Ks[krow * 72 + 32 + quad * 8];
      f32x4 a = {};
      a = __builtin_amdgcn_mfma_f32_16x16x32_bf16(aq0, bk0, a, 0, 0, 0);
      a = __builtin_amdgcn_mfma_f32_16x16x32_bf16(aq1, bk1, a, 0, 0, 0);
      sc[t] = a;
    }
    // scale 1/sqrt(64), mask pad cols (tile 12: keys 192+l16 >= 197)
#pragma unroll
    for (int t = 0; t < 13; t++)
#pragma unroll
      for (int r = 0; r < 4; r++) sc[t][r] *= 0.125f;
    if (l16 >= 5) {
#pragma unroll
      for (int r = 0; r < 4; r++) sc[12][r] = -1e30f;
    }
    // row max (13 tiles in-reg, then across the 16 lanes of this quad)
    f32x4 mx = sc[0];
#pragma unroll
    for (int t = 1; t < 13; t++)
#pragma unroll
      for (int r = 0; r < 4; r++) mx[r] = fmaxf(mx[r], sc[t][r]);
#pragma unroll
    for (int o = 1; o < 16; o <<= 1)
#pragma unroll
      for (int r = 0; r < 4; r++) mx[r] = fmaxf(mx[r], __shfl_xor(mx[r], o));
    // exp + row sum
    f32x4 sum = {};
#pragma unroll
    for (int t = 0; t < 13; t++)
#pragma unroll
      for (int r = 0; r < 4; r++) {
        float p = __expf(sc[t][r] - mx[r]);
        sc[t][r] = p;
        sum[r] += p;
      }
#pragma unroll
    for (int o = 1; o < 16; o <<= 1)
#pragma unroll
      for (int r = 0; r < 4; r++) sum[r] += __shfl_xor(sum[r], o);
    f32x4 rinv;
#pragma unroll
    for (int r = 0; r < 4; r++) rinv[r] = 1.0f / sum[r];
    // P @ V in 32-key slices: write slice (C layout), read pa (A layout),
    // 4 MFMA. Same-wave DS ops execute in order -> no barrier needed.
    f32x4 oacc[4] = {};
#pragma unroll
    for (int ks = 0; ks < 7; ks++) {
#pragma unroll
      for (int tt = 0; tt < 2; tt++) {
        const int t = ks * 2 + tt;
#pragma unroll
        for (int r = 0; r < 4; r++)
          Ps[w][(quad * 4 + r) * 40 + tt * 16 + l16] =
              (t < 13) ? (__bf16)sc[t][r] : z;
      }
      bf16x8 pa = *(const bf16x8*)&Ps[w][l16 * 40 + quad * 8];
#pragma unroll
      for (int c = 0; c < 4; c++) {
        bf16x8 bv = *(const bf16x8*)&Vt[(c * 16 + l16) * 232 + ks * 32 + quad * 8];
        oacc[c] = __builtin_amdgcn_mfma_f32_16x16x32_bf16(pa, bv, oacc[c], 0, 0, 0);
      }
    }
    // epilogue: rows band*16 + quad*4 + r (guarded), cols hd*64 + c*16 + l16
    const int orow = band * 16 + quad * 4;
#pragma unroll
    for (int c = 0; c < 4; c++)
#pragma unroll
      for (int r = 0; r < 4; r++) {
        const int rw = orow + r;
        if (rw < S_)
          ctx[((size_t)b * S_ + rw) * D_ + hd * 64 + c * 16 + l16] =
              __float2bfloat16(oacc[c][r] * rinv[r]);
      }
  }
}

__global__ __launch_bounds__(128) void k_head(const float* __restrict__ h,
                                              const float* __restrict__ g,
                                              const float* __restrict__ bt,
                                              const float* __restrict__ hw,
                                              float* __restrict__ out) {
  const int b = blockIdx.x, t = threadIdx.x;
  const float* row = h + (size_t)b * S_ * D_;
  float x0 = row[t], x1 = row[t + 128], x2 = row[t + 256];
  float s = x0 + x1 + x2;
  float q = x0 * x0 + x1 * x1 + x2 * x2;
#pragma unroll
  for (int o = 32; o; o >>= 1) {
    s += __shfl_xor(s, o);
    q += __shfl_xor(q, o);
  }
  __shared__ float rs[2], rq[2];
  if ((t & 63) == 0) { rs[t >> 6] = s; rq[t >> 6] = q; }
  __syncthreads();
  s = rs[0] + rs[1];
  q = rq[0] + rq[1];
  const float mean = s * (1.f / 384.f);
  const float var = q * (1.f / 384.f) - mean * mean;
  const float rstd = rsqrtf(var + 1e-5f);
  __shared__ float clsn[384];
  clsn[t] = (x0 - mean) * rstd * g[t] + bt[t];
  clsn[t + 128] = (x1 - mean) * rstd * g[t + 128] + bt[t + 128];
  clsn[t + 256] = (x2 - mean) * rstd * g[t + 256] + bt[t + 256];
  __syncthreads();
  if (t < 100) {
    const float* wr = hw + (size_t)t * D_;
    float a = 0.f;
    for (int d = 0; d < 384; d++) a += clsn[d] * wr[d];
    out[b * 100 + t] = a;
  }
}

extern "C" void kernel_launch(void* const* d_in, const int* in_sizes, int n_in,
                              void* d_out, int out_size, void* d_ws, size_t ws_size,
                              hipStream_t stream) {
  (void)in_sizes; (void)n_in; (void)out_size; (void)ws_size;
  const float* x       = (const float*)d_in[0];
  const float* patch_w = (const float*)d_in[1];
  const float* patch_b = (const float*)d_in[2];
  const float* cls_tok = (const float*)d_in[3];
  const float* pos_emb = (const float*)d_in[4];
  const float* ln1_g   = (const float*)d_in[5];
  const float* ln1_b   = (const float*)d_in[6];
  const float* qkv_w   = (const float*)d_in[7];
  const float* qkv_b   = (const float*)d_in[8];
  const float* out_w   = (const float*)d_in[9];
  const float* out_b   = (const float*)d_in[10];
  const float* ln2_g   = (const float*)d_in[11];
  const float* ln2_b   = (const float*)d_in[12];
  const float* fc1_w   = (const float*)d_in[13];
  const float* fc1_b   = (const float*)d_in[14];
  const float* fc2_w   = (const float*)d_in[15];
  const float* fc2_b   = (const float*)d_in[16];
  const float* lnf_g   = (const float*)d_in[17];
  const float* lnf_b   = (const float*)d_in[18];
  const float* head_w  = (const float*)d_in[19];
  float* out = (float*)d_out;

  const size_t R = (size_t)BATCH * S_;  // 25216 token rows
  char* p = (char*)d_ws;
  float* h  = (float*)p; p += R * 384 * 4;       // fp32 residual
  bf16* xn  = (bf16*)p;  p += R * 384 * 2;       // LN output
  bf16* u   = (bf16*)p;  p += R * 1536 * 2;      // union: qkvb|ctxb / hid / patches
  bf16* qkvb = u;                                 // 3*768*197*64 = R*1152
  bf16* ctxb = u + R * 1152;                      // R*384
  bf16* hidb = u;                                 // R*1536 (qkv/ctx dead by then)
  bf16* patches = u;                              // 25088*768 (pre-loop only)
  bf16* wb  = (bf16*)p;                           // bf16 weights
  bf16* patch_wb = wb;                            // 768*384
  bf16* qkv_wb   = patch_wb + 294912;             // 12*1152*384
  bf16* out_wb   = qkv_wb + 5308416;              // 12*384*384
  bf16* fc1_wb   = out_wb + 1769472;              // 12*1536*384
  bf16* fc2_wb   = fc1_wb + 7077888;              // 12*384*1536

  // weight conversion fp32 -> bf16 (same work every launch; graph-safe)
  k_f2b<<<dim3((294912 / 4 + 255) / 256), dim3(256), 0, stream>>>(patch_w, patch_wb, 294912 / 4);
  k_f2b<<<dim3((5308416 / 4 + 255) / 256), dim3(256), 0, stream>>>(qkv_w, qkv_wb, 5308416 / 4);
  k_f2b<<<dim3((1769472 / 4 + 255) / 256), dim3(256), 0, stream>>>(out_w, out_wb, 1769472 / 4);
  k_f2b<<<dim3((7077888 / 4 + 255) / 256), dim3(256), 0, stream>>>(fc1_w, fc1_wb, 7077888 / 4);
  k_f2b<<<dim3((7077888 / 4 + 255) / 256), dim3(256), 0, stream>>>(fc2_w, fc2_wb, 7077888 / 4);

  k_embed_init<<<dim3((BATCH * S_ * D_) / 256), dim3(256), 0, stream>>>(cls_tok, pos_emb, h);
  k_patchify<<<dim3((BATCH * 196 * 768) / 256), dim3(256), 0, stream>>>(x, patches);
  // tok = patches @ patch_w^T + patch_b, accumulated into h (remap rows)
  k_gemm<2><<<dim3(3, 196), dim3(512), 0, stream>>>(patches, patch_wb, patch_b, nullptr, h, 384, 768, 1);

  for (int i = 0; i < 12; i++) {
    k_ln<<<dim3((unsigned)R), dim3(128), 0, stream>>>(h, ln1_g + i * 384, ln1_b + i * 384, xn);
    // qkv in head-major layout (MODE 3)
    k_gemm<3><<<dim3(9, 197), dim3(512), 0, stream>>>(xn, qkv_wb + (size_t)i * 1152 * 384,
                                                      qkv_b + i * 1152, qkvb, nullptr, 1152, 384, 0);
    k_attn<<<dim3(768), dim3(256), 0, stream>>>(qkvb, ctxb);
    k_gemm<2><<<dim3(3, 197), dim3(512), 0, stream>>>(ctxb, out_wb + (size_t)i * 384 * 384,
                                                      out_b + i * 384, nullptr, h, 384, 384, 0);
    k_ln<<<dim3((unsigned)R), dim3(128), 0, stream>>>(h, ln2_g + i * 384, ln2_b + i * 384, xn);
    k_gemm<1><<<dim3(12, 197), dim3(512), 0, stream>>>(xn, fc1_wb + (size_t)i * 1536 * 384,
                                                       fc1_b + i * 1536, hidb, nullptr, 1536, 384, 0);
    k_gemm<2><<<dim3(3, 197), dim3(512), 0, stream>>>(hidb, fc2_wb + (size_t)i * 384 * 1536,
                                                      fc2_b + i * 384, nullptr, h, 384, 1536, 0);
  }
  k_head<<<dim3(128), dim3(128), 0, stream>>>(h, lnf_g, lnf_b, head_w, out);
}